// Round 3
// baseline (1380.952 us; speedup 1.0000x reference)
//
#include <hip/hip_runtime.h>
#include <hip/hip_bf16.h>

// FSAS_26766236188756 — round 3: all-fp32 I/O (reference dtypes), chunked pipeline.
// Per batch, per row-chunk of R rows:
//   k1: 1x1 conv 64->384 for rows [r0-1, r0+R+1) -> hidden_chunk (fp32)
//   k2: depthwise 3x3 SAME -> qkv_chunk rows [r0, r0+R) (fp32)
//   k3: per-8x8-patch circular conv (q (*) k), LayerNorm(C=128), *v, proj 128->64 -> out
// R picked from ws_size (fp32 chunks: R=256 needs ~202 MB ... R=8 needs ~7.1 MB).

#define CC 64
#define HID 384
#define D2 128
#define QPAD 68

// ws: [0, 32768) w_proj^T fp32 [128][64] ; chunk buffers from WBASE
#define WBASE 65536

// K0: transpose w_proj [64][128] -> wpT [128][64]
__global__ __launch_bounds__(256) void k0_wpt(
    const float* __restrict__ wp, float* __restrict__ wpT) {
    int t = threadIdx.x;
    for (int i = t; i < 8192; i += 256) {
        int c = i >> 6, o = i & 63;
        wpT[i] = wp[o * 128 + c];
    }
}

// K1: hidden_chunk[o][lrow][col] = sum_c W[o][c]*x[b][c][grow][col] + bh[o]
// Block: 64 consecutive pixels of one image row x all 384 outputs.
// grid.x = valid_rows*4. grow = lo + (blk>>2); quarter = blk&3.
__global__ __launch_bounds__(256) void k1_pw(
    const float* __restrict__ x, const float* __restrict__ wh,
    const float* __restrict__ bh, float* __restrict__ hidc,
    int b, int lo, int r0, int R) {
    __shared__ float xs[64 * 64];
    int tid = threadIdx.x;
    int g = blockIdx.x;
    int grow = lo + (g >> 2);
    int col0 = (g & 3) << 6;
    int lrow = grow - (r0 - 1);          // 0..R+1
    int pix = tid & 63, grp = tid >> 6;
    for (int m = 0; m < 16; m++) {
        int c = m * 4 + grp;
        xs[c * 64 + pix] = x[(((size_t)(b * CC + c)) << 16) + (grow << 8) + col0 + pix];
    }
    __syncthreads();
    float xr[64];
#pragma unroll
    for (int c = 0; c < 64; c++) xr[c] = xs[c * 64 + pix];
    size_t rowpitch = (size_t)(R + 2) << 8;
    float* outp = hidc + (size_t)lrow * 256 + col0 + pix;
    int o0 = grp * 96;
    for (int oi = 0; oi < 96; oi++) {
        int o = o0 + oi;
        const float* wrow = wh + o * 64;
        float acc = bh[o];
#pragma unroll
        for (int c = 0; c < 64; c++) acc += wrow[c] * xr[c];
        outp[(size_t)o * rowpitch] = acc;
    }
}

// K2: depthwise 3x3 SAME (cross-correlation) + bias. Block = 8 out rows x 1 channel.
__global__ __launch_bounds__(256) void k2_dw(
    const float* __restrict__ hidc, const float* __restrict__ wdw,
    const float* __restrict__ bdw, float* __restrict__ qkvc, int r0, int R) {
    __shared__ float rows[10][258];
    int tid = threadIdx.x;
    int ch = blockIdx.y;
    int lr0 = blockIdx.x * 8;            // local out-row base (0..R-8)
    const float* base = hidc + (size_t)ch * ((size_t)(R + 2) << 8);
    for (int rr = 0; rr < 10; rr++) {
        int lr = lr0 + rr;               // hidden local row 0..R+1
        int grow = r0 - 1 + lr;
        float v = 0.f;
        if (grow >= 0 && grow < 256) v = base[(size_t)lr * 256 + tid];
        rows[rr][1 + tid] = v;
        if (tid == 0) { rows[rr][0] = 0.f; rows[rr][257] = 0.f; }
    }
    __syncthreads();
    float w00 = wdw[ch * 9 + 0], w01 = wdw[ch * 9 + 1], w02 = wdw[ch * 9 + 2];
    float w10 = wdw[ch * 9 + 3], w11 = wdw[ch * 9 + 4], w12 = wdw[ch * 9 + 5];
    float w20 = wdw[ch * 9 + 6], w21 = wdw[ch * 9 + 7], w22 = wdw[ch * 9 + 8];
    float bias = bdw[ch];
    float* ob = qkvc + (size_t)ch * ((size_t)R << 8);
#pragma unroll
    for (int rr = 0; rr < 8; rr++) {
        float acc = bias
            + w00 * rows[rr][tid] + w01 * rows[rr][tid + 1] + w02 * rows[rr][tid + 2]
            + w10 * rows[rr + 1][tid] + w11 * rows[rr + 1][tid + 1] + w12 * rows[rr + 1][tid + 2]
            + w20 * rows[rr + 2][tid] + w21 * rows[rr + 2][tid + 1] + w22 * rows[rr + 2][tid + 2];
        ob[(size_t)(lr0 + rr) * 256 + tid] = acc;
    }
}

// K3: per patch: circular conv per channel (128 ch), LN over 128 ch per pixel,
// * v, proj 128->64. One block per patch within the chunk.
__global__ __launch_bounds__(256) void k3_patch(
    const float* __restrict__ qkvc, const float* __restrict__ wpT,
    const float* __restrict__ bp, const float* __restrict__ lnw,
    const float* __restrict__ lnb, float* __restrict__ out,
    int b, int r0, int R) {
    __shared__ float qb[128 * QPAD];   // q -> t -> normalized*v
    __shared__ float kb[128 * QPAD];   // k -> wpT
    __shared__ float red_s[4][64];
    __shared__ float red_q[4][64];

    int tid = threadIdx.x;
    int pid = blockIdx.x;              // (R/8)*32 patches
    int phl = pid >> 5, pw = pid & 31;
    int pix = tid & 63, cg = tid >> 6;
    int py = pix >> 3, px = pix & 7;
    int lrow = (phl << 3) + py;        // local row within chunk
    int col = (pw << 3) + px;
    size_t cpitch = (size_t)R << 8;
    size_t hwp = (size_t)lrow * 256 + col;

    // Phase A: stage q,k into LDS (row pad 68: 16B-aligned rows)
    for (int j = 0; j < 32; j++) {
        int c = cg * 32 + j;
        qb[c * QPAD + pix] = qkvc[(size_t)c * cpitch + hwp];
        kb[c * QPAD + pix] = qkvc[(size_t)(D2 + c) * cpitch + hwp];
    }
    __syncthreads();

    // Phase B: circular conv. unit=(c,r): thread handles units tid+256u, outputs s=0..7.
    float accv[4][8];
#pragma unroll
    for (int u = 0; u < 4; u++)
#pragma unroll
        for (int s = 0; s < 8; s++) accv[u][s] = 0.f;
#pragma unroll
    for (int u = 0; u < 4; u++) {
        int unit = tid + (u << 8);
        int c = unit >> 3, r = unit & 7;
        const float* qr = qb + c * QPAD;
        const float* kr = kb + c * QPAD;
#pragma unroll 1
        for (int i = 0; i < 8; i++) {
            float4 qa = *(const float4*)(qr + i * 8);
            float4 qc = *(const float4*)(qr + i * 8 + 4);
            int r2 = (r - i) & 7;
            float4 ka = *(const float4*)(kr + r2 * 8);
            float4 kc = *(const float4*)(kr + r2 * 8 + 4);
            float qv[8] = {qa.x, qa.y, qa.z, qa.w, qc.x, qc.y, qc.z, qc.w};
            float kv[8] = {ka.x, ka.y, ka.z, ka.w, kc.x, kc.y, kc.z, kc.w};
#pragma unroll
            for (int j = 0; j < 8; j++)
#pragma unroll
                for (int s = 0; s < 8; s++)
                    accv[u][s] += qv[j] * kv[(s - j) & 7];
        }
    }
    __syncthreads();

    // Phase C: write t into qb; load wpT into kb
#pragma unroll
    for (int u = 0; u < 4; u++) {
        int unit = tid + (u << 8);
        int c = unit >> 3, r = unit & 7;
        float* tr = qb + c * QPAD + r * 8;
#pragma unroll
        for (int s = 0; s < 8; s++) tr[s] = accv[u][s];
    }
    for (int i = tid; i < 8192; i += 256) kb[i] = wpT[i];
    __syncthreads();

    // LN: per-pixel mean/var over 128 channels
    float sum = 0.f, sq = 0.f;
#pragma unroll
    for (int j = 0; j < 32; j++) {
        int c = cg * 32 + j;
        float v = qb[c * QPAD + pix];
        sum += v; sq += v * v;
    }
    red_s[cg][pix] = sum;
    red_q[cg][pix] = sq;
    __syncthreads();
    float ts = red_s[0][pix] + red_s[1][pix] + red_s[2][pix] + red_s[3][pix];
    float tq = red_q[0][pix] + red_q[1][pix] + red_q[2][pix] + red_q[3][pix];
    float mu = ts * (1.f / 128.f);
    float var = tq * (1.f / 128.f) - mu * mu;
    float rsig = rsqrtf(var + 1e-5f);

    // Phase D: t = ((t-mu)*rsig*lnw + lnb) * v
    for (int j = 0; j < 32; j++) {
        int c = cg * 32 + j;
        float vv = qkvc[(size_t)(2 * D2 + c) * cpitch + hwp];
        float tv = qb[c * QPAD + pix];
        float nv = (tv - mu) * rsig * lnw[c] + lnb[c];
        qb[c * QPAD + pix] = nv * vv;
    }
    __syncthreads();

    // Phase E: proj 128->64. thread: pixel pix, outputs o = cg*16..+15
    float pacc[16];
#pragma unroll
    for (int o2 = 0; o2 < 16; o2++) pacc[o2] = bp[cg * 16 + o2];
#pragma unroll 2
    for (int c = 0; c < 128; c++) {
        float tv = qb[c * QPAD + pix];
        const float4* wrow = (const float4*)(kb + c * 64 + cg * 16);
        float4 w0 = wrow[0], w1 = wrow[1], w2 = wrow[2], w3 = wrow[3];
        pacc[0]  += w0.x * tv; pacc[1]  += w0.y * tv; pacc[2]  += w0.z * tv; pacc[3]  += w0.w * tv;
        pacc[4]  += w1.x * tv; pacc[5]  += w1.y * tv; pacc[6]  += w1.z * tv; pacc[7]  += w1.w * tv;
        pacc[8]  += w2.x * tv; pacc[9]  += w2.y * tv; pacc[10] += w2.z * tv; pacc[11] += w2.w * tv;
        pacc[12] += w3.x * tv; pacc[13] += w3.y * tv; pacc[14] += w3.z * tv; pacc[15] += w3.w * tv;
    }
    int grow = r0 + lrow;
    float* ob = out + (((size_t)(b * CC)) << 16) + (size_t)grow * 256 + col;
#pragma unroll
    for (int o2 = 0; o2 < 16; o2++) {
        int o = cg * 16 + o2;
        ob[((size_t)o) << 16] = pacc[o2];
    }
}

extern "C" void kernel_launch(void* const* d_in, const int* in_sizes, int n_in,
                              void* d_out, int out_size, void* d_ws, size_t ws_size,
                              hipStream_t stream) {
    (void)in_sizes; (void)n_in; (void)out_size;
    const float* x   = (const float*)d_in[0];
    const float* wh  = (const float*)d_in[1];
    const float* bh  = (const float*)d_in[2];
    const float* wdw = (const float*)d_in[3];
    const float* bdw = (const float*)d_in[4];
    const float* wp  = (const float*)d_in[5];
    const float* bp  = (const float*)d_in[6];
    const float* lnw = (const float*)d_in[7];
    const float* lnb = (const float*)d_in[8];
    float* out = (float*)d_out;

    char* ws = (char*)d_ws;
    float* wpT = (float*)ws;

    // pick largest R (rows/chunk, divides 256) whose fp32 buffers fit in ws
    int R = 256;
    while (R > 8) {
        size_t need = (size_t)HID * (size_t)(R + 2) * 256 * 4   // hidden_chunk
                    + (size_t)HID * (size_t)R * 256 * 4;        // qkv_chunk
        if (WBASE + need <= ws_size) break;
        R >>= 1;
    }
    size_t hid_bytes = (size_t)HID * (size_t)(R + 2) * 256 * 4;
    float* hidc = (float*)(ws + WBASE);
    float* qkvc = (float*)(ws + WBASE + hid_bytes);
    int nchunks = 256 / R;

    k0_wpt<<<dim3(1), dim3(256), 0, stream>>>(wp, wpT);

    for (int b = 0; b < 4; b++) {
        for (int ck = 0; ck < nchunks; ck++) {
            int r0 = ck * R;
            int lo = r0 - 1; if (lo < 0) lo = 0;
            int hi = r0 + R + 1; if (hi > 256) hi = 256;
            int valid = hi - lo;
            k1_pw<<<dim3(valid * 4), dim3(256), 0, stream>>>(x, wh, bh, hidc, b, lo, r0, R);
            k2_dw<<<dim3(R / 8, HID), dim3(256), 0, stream>>>(hidc, wdw, bdw, qkvc, r0, R);
            k3_patch<<<dim3((R / 8) * 32), dim3(256), 0, stream>>>(qkvc, wpT, bp, lnw, lnb, out, b, r0, R);
        }
    }
}

// Round 4
// 654.198 us; speedup vs baseline: 2.1109x; 2.1109x over previous
//
#include <hip/hip_runtime.h>
#include <hip/hip_bf16.h>

// FSAS_26766236188756 — round 4: bf16 MFMA k1 + bf16 intermediates.
// kx: x [b][c][hw] fp32 -> XT [b][hw][c] bf16 (transpose+convert)
// k0: weight prep: wpT fp32 transpose + WS (MFMA-swizzled bf16 w_hidden frags)
// per batch: k1 MFMA GEMM 64->384 (bf16 out) -> k2 dw3x3 (bf16) -> k3 patch ops (fp32 out)

typedef unsigned short ushort;
typedef __attribute__((ext_vector_type(8))) short short8;
typedef __attribute__((ext_vector_type(4))) float floatx4;

#define CC 64
#define HID 384
#define D2 128
#define HW 65536
#define QPAD 68

// ws layout (bytes):
//   [0,       32768)  wpT fp32 [128][64]
//   [32768,   81920)  WS  bf16 [24 mtile][2 ks][64 lane][8] swizzled w_hidden
//   [131072, +33.5MB) XT  bf16 [4][HW][64]
//   then hid bf16 [384][HW] (one batch), qkv bf16 [384][HW] (one batch)
#define WPT_OFF 0
#define WS_OFF  32768
#define XT_OFF  131072
#define XT_BYTES (4ull * HW * 64 * 2)            // 33,554,432
#define HID_OFF (XT_OFF + XT_BYTES)              // 33,685,504
#define HID_BYTES (384ull * HW * 2)              // 50,331,648
#define QKV_OFF (HID_OFF + HID_BYTES)            // 84,017,152

__device__ __forceinline__ float bu2f(ushort u) {
    union { float f; unsigned i; } v; v.i = ((unsigned)u) << 16; return v.f;
}
__device__ __forceinline__ ushort f2bu(float f) {
    __hip_bfloat16 h = __float2bfloat16(f);
    return *(ushort*)&h;
}

// kx: transpose+convert x -> XT. Block: 256 threads, each owns one hw; 8 c-chunks.
__global__ __launch_bounds__(256) void kx_tr(
    const float* __restrict__ x, ushort* __restrict__ XT) {
    int b = blockIdx.y;
    int hw = blockIdx.x * 256 + threadIdx.x;
    const float* xb = x + ((size_t)b * CC) * HW;
    ushort* XTb = XT + ((size_t)b * HW + hw) * 64;
#pragma unroll 2
    for (int c0 = 0; c0 < 64; c0 += 8) {
        ushort v[8];
#pragma unroll
        for (int j = 0; j < 8; j++)
            v[j] = f2bu(xb[(size_t)(c0 + j) * HW + hw]);
        *(short8*)(XTb + c0) = *(short8*)v;
    }
}

// k0: wpT transpose (fp32) + WS swizzle (bf16 MFMA A-frags of w_hidden)
__global__ __launch_bounds__(256) void k0_prep(
    const float* __restrict__ wp, const float* __restrict__ wh,
    float* __restrict__ wpT, ushort* __restrict__ WS) {
    int t = threadIdx.x;
    for (int i = t; i < 8192; i += 256) {
        int c = i >> 6, o = i & 63;
        wpT[i] = wp[o * 128 + c];
    }
    // WS[idx]: idx = ((mt*2+ks)*64+lane)*8+j  <->  W[o][k], o=mt*16+(lane&15),
    // k = ks*32 + (lane>>4)*8 + j
    for (int i = t; i < 24576; i += 256) {
        int j = i & 7;
        int lane = (i >> 3) & 63;
        int ks = (i >> 9) & 1;
        int mt = i >> 10;
        int o = mt * 16 + (lane & 15);
        int k = ks * 32 + ((lane >> 4) << 3) + j;
        WS[i] = f2bu(wh[o * 64 + k]);
    }
}

// k1: hidden[o][pix] = sum_c W[o][c]*x[c][pix] + bh[o], via 16x16x32 bf16 MFMA.
// Block: 4 waves; wave = 64 out x 64 pix. Block = 64 out x 256 pix.
// grid: (HW/256, 384/64)
__global__ __launch_bounds__(256) void k1_mfma(
    const ushort* __restrict__ XT, const ushort* __restrict__ WS,
    const float* __restrict__ bh, ushort* __restrict__ hid) {
    int tid = threadIdx.x;
    int lane = tid & 63, wave = tid >> 6;
    int lane15 = lane & 15, quad = lane >> 4;
    int pix0 = blockIdx.x * 256 + wave * 64;
    int o0 = blockIdx.y * 64;

    short8 a[4][2];
#pragma unroll
    for (int mt = 0; mt < 4; mt++) {
        int mtg = (o0 >> 4) + mt;
#pragma unroll
        for (int ks = 0; ks < 2; ks++)
            a[mt][ks] = *(const short8*)(WS + ((((mtg << 1) + ks) << 6) + lane) * 8);
    }
    floatx4 acc[4][4];
#pragma unroll
    for (int mt = 0; mt < 4; mt++)
#pragma unroll
        for (int nt = 0; nt < 4; nt++)
            acc[mt][nt] = (floatx4){0.f, 0.f, 0.f, 0.f};

#pragma unroll
    for (int nt = 0; nt < 4; nt++) {
        const ushort* bp0 = XT + ((size_t)(pix0 + nt * 16 + lane15) << 6) + quad * 8;
        short8 b0 = *(const short8*)(bp0);
        short8 b1 = *(const short8*)(bp0 + 32);
#pragma unroll
        for (int mt = 0; mt < 4; mt++) {
            acc[mt][nt] = __builtin_amdgcn_mfma_f32_16x16x32_bf16(a[mt][0], b0, acc[mt][nt], 0, 0, 0);
            acc[mt][nt] = __builtin_amdgcn_mfma_f32_16x16x32_bf16(a[mt][1], b1, acc[mt][nt], 0, 0, 0);
        }
    }
    // epilogue: D row = quad*4+reg (out), col = lane15 (pix)
#pragma unroll
    for (int mt = 0; mt < 4; mt++) {
        int obase = o0 + mt * 16 + quad * 4;
        float b0 = bh[obase], b1 = bh[obase + 1], b2 = bh[obase + 2], b3 = bh[obase + 3];
#pragma unroll
        for (int nt = 0; nt < 4; nt++) {
            int pix = pix0 + nt * 16 + lane15;
            hid[(size_t)(obase + 0) * HW + pix] = f2bu(acc[mt][nt][0] + b0);
            hid[(size_t)(obase + 1) * HW + pix] = f2bu(acc[mt][nt][1] + b1);
            hid[(size_t)(obase + 2) * HW + pix] = f2bu(acc[mt][nt][2] + b2);
            hid[(size_t)(obase + 3) * HW + pix] = f2bu(acc[mt][nt][3] + b3);
        }
    }
}

// k2: depthwise 3x3 SAME + bias. Block = 8 out rows x 1 channel. grid (32, 384).
__global__ __launch_bounds__(256) void k2_dw(
    const ushort* __restrict__ hid, const float* __restrict__ wdw,
    const float* __restrict__ bdw, ushort* __restrict__ qkv) {
    __shared__ float rows[10][258];
    int tid = threadIdx.x;
    int ch = blockIdx.y;
    int r0 = blockIdx.x * 8;
    const ushort* base = hid + (size_t)ch * HW;
    for (int rr = 0; rr < 10; rr++) {
        int r = r0 - 1 + rr;
        float v = 0.f;
        if (r >= 0 && r < 256) v = bu2f(base[(r << 8) + tid]);
        rows[rr][1 + tid] = v;
        if (tid == 0) { rows[rr][0] = 0.f; rows[rr][257] = 0.f; }
    }
    __syncthreads();
    float w00 = wdw[ch * 9 + 0], w01 = wdw[ch * 9 + 1], w02 = wdw[ch * 9 + 2];
    float w10 = wdw[ch * 9 + 3], w11 = wdw[ch * 9 + 4], w12 = wdw[ch * 9 + 5];
    float w20 = wdw[ch * 9 + 6], w21 = wdw[ch * 9 + 7], w22 = wdw[ch * 9 + 8];
    float bias = bdw[ch];
    ushort* ob = qkv + (size_t)ch * HW;
#pragma unroll
    for (int rr = 0; rr < 8; rr++) {
        float acc = bias
            + w00 * rows[rr][tid] + w01 * rows[rr][tid + 1] + w02 * rows[rr][tid + 2]
            + w10 * rows[rr + 1][tid] + w11 * rows[rr + 1][tid + 1] + w12 * rows[rr + 1][tid + 2]
            + w20 * rows[rr + 2][tid] + w21 * rows[rr + 2][tid + 1] + w22 * rows[rr + 2][tid + 2];
        ob[((r0 + rr) << 8) + tid] = f2bu(acc);
    }
}

// k3: per patch: circular conv (128 ch), LN over 128 ch per pixel, *v, proj 128->64.
// One block per 8x8 patch; grid 1024 per batch.
__global__ __launch_bounds__(256) void k3_patch(
    const ushort* __restrict__ qkv, const float* __restrict__ wpT,
    const float* __restrict__ bp, const float* __restrict__ lnw,
    const float* __restrict__ lnb, float* __restrict__ out, int b) {
    __shared__ float qb[128 * QPAD];   // q -> t -> normalized*v
    __shared__ float kb[128 * QPAD];   // k -> wpT
    __shared__ float red_s[4][64];
    __shared__ float red_q[4][64];

    int tid = threadIdx.x;
    int pid = blockIdx.x;
    int ph = pid >> 5, pw = pid & 31;
    int pix = tid & 63, cg = tid >> 6;
    int py = pix >> 3, px = pix & 7;
    int row = (ph << 3) + py;
    int col = (pw << 3) + px;
    size_t hwp = (size_t)row * 256 + col;

    // Phase A: stage q,k into LDS
    for (int j = 0; j < 32; j++) {
        int c = cg * 32 + j;
        qb[c * QPAD + pix] = bu2f(qkv[(size_t)c * HW + hwp]);
        kb[c * QPAD + pix] = bu2f(qkv[(size_t)(D2 + c) * HW + hwp]);
    }
    __syncthreads();

    // Phase B: circular conv. unit=(c,r): thread handles units tid+256u, outputs s=0..7.
    float accv[4][8];
#pragma unroll
    for (int u = 0; u < 4; u++)
#pragma unroll
        for (int s = 0; s < 8; s++) accv[u][s] = 0.f;
#pragma unroll
    for (int u = 0; u < 4; u++) {
        int unit = tid + (u << 8);
        int c = unit >> 3, r = unit & 7;
        const float* qr = qb + c * QPAD;
        const float* kr = kb + c * QPAD;
#pragma unroll 1
        for (int i = 0; i < 8; i++) {
            float4 qa = *(const float4*)(qr + i * 8);
            float4 qc = *(const float4*)(qr + i * 8 + 4);
            int r2 = (r - i) & 7;
            float4 ka = *(const float4*)(kr + r2 * 8);
            float4 kc = *(const float4*)(kr + r2 * 8 + 4);
            float qv[8] = {qa.x, qa.y, qa.z, qa.w, qc.x, qc.y, qc.z, qc.w};
            float kv[8] = {ka.x, ka.y, ka.z, ka.w, kc.x, kc.y, kc.z, kc.w};
#pragma unroll
            for (int j = 0; j < 8; j++)
#pragma unroll
                for (int s = 0; s < 8; s++)
                    accv[u][s] += qv[j] * kv[(s - j) & 7];
        }
    }
    __syncthreads();

    // Phase C: write t into qb; load wpT into kb
#pragma unroll
    for (int u = 0; u < 4; u++) {
        int unit = tid + (u << 8);
        int c = unit >> 3, r = unit & 7;
        float* tr = qb + c * QPAD + r * 8;
#pragma unroll
        for (int s = 0; s < 8; s++) tr[s] = accv[u][s];
    }
    for (int i = tid; i < 8192; i += 256) kb[i] = wpT[i];
    __syncthreads();

    // LN: per-pixel mean/var over 128 channels
    float sum = 0.f, sq = 0.f;
#pragma unroll
    for (int j = 0; j < 32; j++) {
        int c = cg * 32 + j;
        float v = qb[c * QPAD + pix];
        sum += v; sq += v * v;
    }
    red_s[cg][pix] = sum;
    red_q[cg][pix] = sq;
    __syncthreads();
    float ts = red_s[0][pix] + red_s[1][pix] + red_s[2][pix] + red_s[3][pix];
    float tq = red_q[0][pix] + red_q[1][pix] + red_q[2][pix] + red_q[3][pix];
    float mu = ts * (1.f / 128.f);
    float var = tq * (1.f / 128.f) - mu * mu;
    float rsig = rsqrtf(var + 1e-5f);

    // Phase D: t = ((t-mu)*rsig*lnw + lnb) * v
    for (int j = 0; j < 32; j++) {
        int c = cg * 32 + j;
        float vv = bu2f(qkv[(size_t)(2 * D2 + c) * HW + hwp]);
        float tv = qb[c * QPAD + pix];
        float nv = (tv - mu) * rsig * lnw[c] + lnb[c];
        qb[c * QPAD + pix] = nv * vv;
    }
    __syncthreads();

    // Phase E: proj 128->64. thread: pixel pix, outputs o = cg*16..+15
    float pacc[16];
#pragma unroll
    for (int o2 = 0; o2 < 16; o2++) pacc[o2] = bp[cg * 16 + o2];
#pragma unroll 2
    for (int c = 0; c < 128; c++) {
        float tv = qb[c * QPAD + pix];
        const float4* wrow = (const float4*)(kb + c * 64 + cg * 16);
        float4 w0 = wrow[0], w1 = wrow[1], w2 = wrow[2], w3 = wrow[3];
        pacc[0]  += w0.x * tv; pacc[1]  += w0.y * tv; pacc[2]  += w0.z * tv; pacc[3]  += w0.w * tv;
        pacc[4]  += w1.x * tv; pacc[5]  += w1.y * tv; pacc[6]  += w1.z * tv; pacc[7]  += w1.w * tv;
        pacc[8]  += w2.x * tv; pacc[9]  += w2.y * tv; pacc[10] += w2.z * tv; pacc[11] += w2.w * tv;
        pacc[12] += w3.x * tv; pacc[13] += w3.y * tv; pacc[14] += w3.z * tv; pacc[15] += w3.w * tv;
    }
    float* ob = out + (((size_t)(b * CC)) << 16) + hwp;
#pragma unroll
    for (int o2 = 0; o2 < 16; o2++) {
        int o = cg * 16 + o2;
        ob[((size_t)o) << 16] = pacc[o2];
    }
}

extern "C" void kernel_launch(void* const* d_in, const int* in_sizes, int n_in,
                              void* d_out, int out_size, void* d_ws, size_t ws_size,
                              hipStream_t stream) {
    (void)in_sizes; (void)n_in; (void)out_size; (void)ws_size;
    const float* x   = (const float*)d_in[0];
    const float* wh  = (const float*)d_in[1];
    const float* bh  = (const float*)d_in[2];
    const float* wdw = (const float*)d_in[3];
    const float* bdw = (const float*)d_in[4];
    const float* wp  = (const float*)d_in[5];
    const float* bp  = (const float*)d_in[6];
    const float* lnw = (const float*)d_in[7];
    const float* lnb = (const float*)d_in[8];
    float* out = (float*)d_out;

    char* ws = (char*)d_ws;
    float* wpT = (float*)(ws + WPT_OFF);
    ushort* WS = (ushort*)(ws + WS_OFF);
    ushort* XT = (ushort*)(ws + XT_OFF);
    ushort* hid = (ushort*)(ws + HID_OFF);
    ushort* qkv = (ushort*)(ws + QKV_OFF);

    kx_tr<<<dim3(256, 4), dim3(256), 0, stream>>>(x, XT);
    k0_prep<<<dim3(1), dim3(256), 0, stream>>>(wp, wh, wpT, WS);

    for (int b = 0; b < 4; b++) {
        k1_mfma<<<dim3(256, 6), dim3(256), 0, stream>>>(
            XT + (size_t)b * HW * 64, WS, bh, hid);
        k2_dw<<<dim3(32, HID), dim3(256), 0, stream>>>(hid, wdw, bdw, qkv);
        k3_patch<<<dim3(1024), dim3(256), 0, stream>>>(qkv, wpT, bp, lnw, lnb, out, b);
    }
}

// Round 5
// 649.473 us; speedup vs baseline: 2.1263x; 1.0073x over previous
//
#include <hip/hip_runtime.h>
#include <hip/hip_bf16.h>

// FSAS_26766236188756 — round 5: patch-major qkv + conflict-free k3.
// kx: x [b][c][hw] fp32 -> XT [b][hw][c] bf16
// k0: wpT fp32 transpose [128][64]
// k1: MFMA 1x1 conv 64->384, hid bf16 [384][HW] row-major
// k2: dw 3x3 -> qkv bf16 PATCH-MAJOR [384][1024 patches][64 px]
// k3: per-patch circ conv + LN + *v + proj -> out fp32

typedef unsigned short ushort;
typedef __attribute__((ext_vector_type(8))) short short8;
typedef __attribute__((ext_vector_type(4))) float floatx4;

#define CC 64
#define HID 384
#define HW 65536
#define QS 66      // qb/kb row stride (floats)
#define TS 68      // t row stride (floats)

#define WPT_OFF 0
#define XT_OFF  131072
#define XT_BYTES (4ull * HW * 64 * 2)
#define HID_OFF (XT_OFF + XT_BYTES)
#define HID_BYTES (384ull * HW * 2)
#define QKV_OFF (HID_OFF + HID_BYTES)

__device__ __forceinline__ float bu2f(ushort u) {
    union { float f; unsigned i; } v; v.i = ((unsigned)u) << 16; return v.f;
}
__device__ __forceinline__ ushort f2bu(float f) {
    __hip_bfloat16 h = __float2bfloat16(f);
    return *(ushort*)&h;
}

__global__ __launch_bounds__(256) void kx_tr(
    const float* __restrict__ x, ushort* __restrict__ XT) {
    int b = blockIdx.y;
    int hw = blockIdx.x * 256 + threadIdx.x;
    const float* xb = x + ((size_t)b * CC) * HW;
    ushort* XTb = XT + ((size_t)b * HW + hw) * 64;
#pragma unroll 2
    for (int c0 = 0; c0 < 64; c0 += 8) {
        ushort v[8];
#pragma unroll
        for (int j = 0; j < 8; j++)
            v[j] = f2bu(xb[(size_t)(c0 + j) * HW + hw]);
        *(short8*)(XTb + c0) = *(short8*)v;
    }
}

// k0: wpT [c][o] = wp[o][c] fp32; WS mfma-swizzled w_hidden bf16
__global__ __launch_bounds__(256) void k0_prep(
    const float* __restrict__ wp, const float* __restrict__ wh,
    float* __restrict__ wpT, ushort* __restrict__ WS) {
    int t = threadIdx.x;
    for (int i = t; i < 8192; i += 256) {
        int c = i >> 6, o = i & 63;
        wpT[i] = wp[o * 128 + c];
    }
    for (int i = t; i < 24576; i += 256) {
        int j = i & 7;
        int lane = (i >> 3) & 63;
        int ks = (i >> 9) & 1;
        int mt = i >> 10;
        int o = mt * 16 + (lane & 15);
        int k = ks * 32 + ((lane >> 4) << 3) + j;
        WS[i] = f2bu(wh[o * 64 + k]);
    }
}

#define WS_OFF 32768

// k1: MFMA GEMM 64->384. Block 4 waves: 64 out x 256 pix.
__global__ __launch_bounds__(256) void k1_mfma(
    const ushort* __restrict__ XT, const ushort* __restrict__ WS,
    const float* __restrict__ bh, ushort* __restrict__ hid) {
    int tid = threadIdx.x;
    int lane = tid & 63, wave = tid >> 6;
    int lane15 = lane & 15, quad = lane >> 4;
    int pix0 = blockIdx.x * 256 + wave * 64;
    int o0 = blockIdx.y * 64;

    short8 a[4][2];
#pragma unroll
    for (int mt = 0; mt < 4; mt++) {
        int mtg = (o0 >> 4) + mt;
#pragma unroll
        for (int ks = 0; ks < 2; ks++)
            a[mt][ks] = *(const short8*)(WS + ((((mtg << 1) + ks) << 6) + lane) * 8);
    }
    floatx4 acc[4][4];
#pragma unroll
    for (int mt = 0; mt < 4; mt++)
#pragma unroll
        for (int nt = 0; nt < 4; nt++)
            acc[mt][nt] = (floatx4){0.f, 0.f, 0.f, 0.f};

#pragma unroll
    for (int nt = 0; nt < 4; nt++) {
        const ushort* bp0 = XT + ((size_t)(pix0 + nt * 16 + lane15) << 6) + quad * 8;
        short8 b0 = *(const short8*)(bp0);
        short8 b1 = *(const short8*)(bp0 + 32);
#pragma unroll
        for (int mt = 0; mt < 4; mt++) {
            acc[mt][nt] = __builtin_amdgcn_mfma_f32_16x16x32_bf16(a[mt][0], b0, acc[mt][nt], 0, 0, 0);
            acc[mt][nt] = __builtin_amdgcn_mfma_f32_16x16x32_bf16(a[mt][1], b1, acc[mt][nt], 0, 0, 0);
        }
    }
#pragma unroll
    for (int mt = 0; mt < 4; mt++) {
        int obase = o0 + mt * 16 + quad * 4;
        float b0 = bh[obase], b1 = bh[obase + 1], b2 = bh[obase + 2], b3 = bh[obase + 3];
#pragma unroll
        for (int nt = 0; nt < 4; nt++) {
            int pix = pix0 + nt * 16 + lane15;
            hid[(size_t)(obase + 0) * HW + pix] = f2bu(acc[mt][nt][0] + b0);
            hid[(size_t)(obase + 1) * HW + pix] = f2bu(acc[mt][nt][1] + b1);
            hid[(size_t)(obase + 2) * HW + pix] = f2bu(acc[mt][nt][2] + b2);
            hid[(size_t)(obase + 3) * HW + pix] = f2bu(acc[mt][nt][3] + b3);
        }
    }
}

// k2: dw 3x3 SAME + bias -> qkv PATCH-MAJOR [ch][patch][64].
// Block = 8 rows (one patch-row) x 1 ch. grid (32, 384).
__global__ __launch_bounds__(256) void k2_dw(
    const ushort* __restrict__ hid, const float* __restrict__ wdw,
    const float* __restrict__ bdw, ushort* __restrict__ qkv) {
    __shared__ float rows[10][258];
    __shared__ ushort stg[8 * 264];
    int tid = threadIdx.x;
    int ch = blockIdx.y;
    int pr = blockIdx.x;               // patch-row 0..31
    int r0 = pr * 8;
    const ushort* base = hid + (size_t)ch * HW;
    for (int rr = 0; rr < 10; rr++) {
        int r = r0 - 1 + rr;
        float v = 0.f;
        if (r >= 0 && r < 256) v = bu2f(base[(r << 8) + tid]);
        rows[rr][1 + tid] = v;
        if (tid == 0) { rows[rr][0] = 0.f; rows[rr][257] = 0.f; }
    }
    __syncthreads();
    float w00 = wdw[ch * 9 + 0], w01 = wdw[ch * 9 + 1], w02 = wdw[ch * 9 + 2];
    float w10 = wdw[ch * 9 + 3], w11 = wdw[ch * 9 + 4], w12 = wdw[ch * 9 + 5];
    float w20 = wdw[ch * 9 + 6], w21 = wdw[ch * 9 + 7], w22 = wdw[ch * 9 + 8];
    float bias = bdw[ch];
#pragma unroll
    for (int rr = 0; rr < 8; rr++) {
        float acc = bias
            + w00 * rows[rr][tid] + w01 * rows[rr][tid + 1] + w02 * rows[rr][tid + 2]
            + w10 * rows[rr + 1][tid] + w11 * rows[rr + 1][tid + 1] + w12 * rows[rr + 1][tid + 2]
            + w20 * rows[rr + 2][tid] + w21 * rows[rr + 2][tid + 1] + w22 * rows[rr + 2][tid + 2];
        stg[rr * 264 + tid] = f2bu(acc);
    }
    __syncthreads();
    // patch-major writeout: thread t -> 8 contiguous ushorts (fully coalesced 4KB)
    short8 v = *(const short8*)(stg + (tid & 7) * 264 + (tid >> 3) * 8);
    *(short8*)(qkv + (size_t)ch * HW + (size_t)pr * 2048 + tid * 8) = v;
}

// k3: per-patch circ conv + LN + *v + proj. qkv patch-major.
__global__ __launch_bounds__(256, 2) void k3_patch(
    const ushort* __restrict__ qkv, const float* __restrict__ wpTg,
    const float* __restrict__ bp, const float* __restrict__ lnw,
    const float* __restrict__ lnb, float* __restrict__ out, int b) {
    __shared__ float SH[17408];
    float* qb = SH;                 // [128][66]
    float* kb = SH + 8448;          // [128][66]
    float* tb = SH;                 // [128][68] overlay (after B)
    float* wp = SH + 8704;          // [128][64] overlay (after B)
    float* red = SH + 16896;        // 512

    int tid = threadIdx.x;
    int p = blockIdx.x;             // patch 0..1023
    int prow = p >> 5, pcol = p & 31;

    // Phase A: coalesced patch-major loads -> fp32 LDS (stride 66, b64-friendly)
#pragma unroll
    for (int m = 0; m < 4; m++) {
        int f = m * 256 + tid;
        int c = f >> 3;
        int i8 = (f & 7) * 8;
        short8 qv = *(const short8*)(qkv + (size_t)c * HW + (size_t)p * 64 + i8);
        short8 kv = *(const short8*)(qkv + (size_t)(128 + c) * HW + (size_t)p * 64 + i8);
        float* qd = qb + c * QS + i8;
        float* kd = kb + c * QS + i8;
#pragma unroll
        for (int j2 = 0; j2 < 4; j2++) {
            float2 qf = {bu2f(((ushort*)&qv)[2 * j2]), bu2f(((ushort*)&qv)[2 * j2 + 1])};
            float2 kf = {bu2f(((ushort*)&kv)[2 * j2]), bu2f(((ushort*)&kv)[2 * j2 + 1])};
            *(float2*)(qd + 2 * j2) = qf;
            *(float2*)(kd + 2 * j2) = kf;
        }
    }
    __syncthreads();

    // Phase B: 2D circular conv. thread = (channel c, col-half h).
    int c = tid >> 1, h = tid & 1;
    float qr[64];
    {
        const float* qrow = qb + c * QS;
#pragma unroll
        for (int j2 = 0; j2 < 32; j2++) {
            float2 v = *(const float2*)(qrow + 2 * j2);
            qr[2 * j2] = v.x; qr[2 * j2 + 1] = v.y;
        }
    }
    float acc[8][4];
#pragma unroll
    for (int r = 0; r < 8; r++)
#pragma unroll
        for (int sc = 0; sc < 4; sc++) acc[r][sc] = 0.f;
    {
        const float* krow = kb + c * QS;
#pragma unroll 2
        for (int m = 0; m < 8; m++) {
            float kr[8];   // kr[v] = k[c][m][(v+4h)&7]
#pragma unroll
            for (int u2 = 0; u2 < 4; u2++) {
                int colo = (u2 * 2 + 4 * h) & 7;
                float2 v = *(const float2*)(krow + m * 8 + colo);
                kr[u2 * 2] = v.x; kr[u2 * 2 + 1] = v.y;
            }
#pragma unroll
            for (int r = 0; r < 8; r++) {
                int i = (r - m) & 7;
#pragma unroll
                for (int sc = 0; sc < 4; sc++)
#pragma unroll
                    for (int j = 0; j < 8; j++)
                        acc[r][sc] += qr[i * 8 + j] * kr[(sc - j) & 7];
            }
        }
    }
    __syncthreads();

    // Phase C: t -> LDS (stride 68); wpT global -> LDS
#pragma unroll
    for (int r = 0; r < 8; r++) {
        float4 v = {acc[r][0], acc[r][1], acc[r][2], acc[r][3]};
        *(float4*)(tb + c * TS + r * 8 + h * 4) = v;
    }
#pragma unroll 4
    for (int j = 0; j < 32; j++)
        wp[j * 256 + tid] = wpTg[j * 256 + tid];
    __syncthreads();

    // LN: per-pixel stats over 128 ch
    int pix = tid & 63, cg = tid >> 6;
    float sum = 0.f, sq = 0.f;
#pragma unroll
    for (int j = 0; j < 32; j++) {
        int cc = cg * 32 + j;
        float v = tb[cc * TS + pix];
        sum += v; sq += v * v;
    }
    red[cg * 64 + pix] = sum;
    red[256 + cg * 64 + pix] = sq;
    __syncthreads();
    float ts = red[pix] + red[64 + pix] + red[128 + pix] + red[192 + pix];
    float tq = red[256 + pix] + red[320 + pix] + red[384 + pix] + red[448 + pix];
    float mu = ts * (1.f / 128.f);
    float var = tq * (1.f / 128.f) - mu * mu;
    float rsig = rsqrtf(var + 1e-5f);

    // Phase D: t = ((t-mu)*rsig*lnw + lnb) * v   (in-place, per-pixel exclusive)
#pragma unroll 4
    for (int j = 0; j < 32; j++) {
        int cc = cg * 32 + j;
        float vv = bu2f(qkv[(size_t)(256 + cc) * HW + (size_t)p * 64 + pix]);
        float tv = tb[cc * TS + pix];
        tb[cc * TS + pix] = ((tv - mu) * rsig * lnw[cc] + lnb[cc]) * vv;
    }
    __syncthreads();

    // Phase E: proj 128->64, thread tile 4 out x 4 pix (all LDS reads 2-way/free)
    int oi = tid & 15, pg = tid >> 4;
    int o0 = oi * 4, pix0 = pg * 4;
    float pe[4][4];
#pragma unroll
    for (int oo = 0; oo < 4; oo++) {
        float bb = bp[o0 + oo];
#pragma unroll
        for (int pp = 0; pp < 4; pp++) pe[oo][pp] = bb;
    }
#pragma unroll 4
    for (int cc = 0; cc < 128; cc++) {
        float4 wv = *(const float4*)(wp + cc * 64 + o0);
        float4 tv = *(const float4*)(tb + cc * TS + pix0);
        pe[0][0] += wv.x * tv.x; pe[0][1] += wv.x * tv.y; pe[0][2] += wv.x * tv.z; pe[0][3] += wv.x * tv.w;
        pe[1][0] += wv.y * tv.x; pe[1][1] += wv.y * tv.y; pe[1][2] += wv.y * tv.z; pe[1][3] += wv.y * tv.w;
        pe[2][0] += wv.z * tv.x; pe[2][1] += wv.z * tv.y; pe[2][2] += wv.z * tv.z; pe[2][3] += wv.z * tv.w;
        pe[3][0] += wv.w * tv.x; pe[3][1] += wv.w * tv.y; pe[3][2] += wv.w * tv.z; pe[3][3] += wv.w * tv.w;
    }
    int row = (prow << 3) + (pix0 >> 3);
    int col = (pcol << 3) + (pix0 & 7);
#pragma unroll
    for (int oo = 0; oo < 4; oo++) {
        float4 v = {pe[oo][0], pe[oo][1], pe[oo][2], pe[oo][3]};
        *(float4*)(out + (((size_t)(b * CC + o0 + oo)) << 16) + row * 256 + col) = v;
    }
}

extern "C" void kernel_launch(void* const* d_in, const int* in_sizes, int n_in,
                              void* d_out, int out_size, void* d_ws, size_t ws_size,
                              hipStream_t stream) {
    (void)in_sizes; (void)n_in; (void)out_size; (void)ws_size;
    const float* x   = (const float*)d_in[0];
    const float* wh  = (const float*)d_in[1];
    const float* bh  = (const float*)d_in[2];
    const float* wdw = (const float*)d_in[3];
    const float* bdw = (const float*)d_in[4];
    const float* wp  = (const float*)d_in[5];
    const float* bp  = (const float*)d_in[6];
    const float* lnw = (const float*)d_in[7];
    const float* lnb = (const float*)d_in[8];
    float* out = (float*)d_out;

    char* ws = (char*)d_ws;
    float* wpT = (float*)(ws + WPT_OFF);
    ushort* WS = (ushort*)(ws + WS_OFF);
    ushort* XT = (ushort*)(ws + XT_OFF);
    ushort* hid = (ushort*)(ws + HID_OFF);
    ushort* qkv = (ushort*)(ws + QKV_OFF);

    kx_tr<<<dim3(256, 4), dim3(256), 0, stream>>>(x, XT);
    k0_prep<<<dim3(1), dim3(256), 0, stream>>>(wp, wh, wpT, WS);

    for (int b = 0; b < 4; b++) {
        k1_mfma<<<dim3(256, 6), dim3(256), 0, stream>>>(
            XT + (size_t)b * HW * 64, WS, bh, hid);
        k2_dw<<<dim3(32, HID), dim3(256), 0, stream>>>(hid, wdw, bdw, qkv);
        k3_patch<<<dim3(1024), dim3(256), 0, stream>>>(qkv, wpT, bp, lnw, lnb, out, b);
    }
}